// Round 7
// baseline (568.891 us; speedup 1.0000x reference)
//
#include <hip/hip_runtime.h>

// out[b,o] = sum_e ( relu(relu(x[b,e,:]@W1[e]+b1[e])@W2[e]+b2[e]) @ W3[e] + b3[e] )
// E=16, DIN=128, H=512, DOUT=64, B=8192.  94.5 GFLOP.
//
// R7 = R6 with __launch_bounds__(512, 1).
//   R6 spilled: VGPR_Count pinned at the 128 cap from (512,2) [2 blocks/CU => 4 waves/SIMD
//   => 512/4 = 128 regs], FETCH 880 MB / WRITE 242 MB of HBM scratch traffic, MfmaUtil 8.5%.
//   LDS (160 KB) already forces 1 WG/CU, so (512,1) [1 block/CU => 2 waves/SIMD => 256-reg cap]
//   costs nothing and fits the persistent loop's ~220-reg live set without spill.
// R6 design (unchanged): persistent 256 WGs (1/CU), expert fixed per WG (XCD-affine),
//   8 rounds over batch; LDS 160KB = X dbuf 2x16KB + H1 64KB + H2 64KB; 2 barriers/round;
//   X(r+1) staged mid-L2-loop; L3 rolling lookahead-3 in 4 slots for A and B.

#define NE   16
#define NDIN 128
#define NH   512
#define NDO  64
#define NB   8192

using bf16x8 = __attribute__((ext_vector_type(8))) __bf16;
using f32x4  = __attribute__((ext_vector_type(4))) float;

__device__ __forceinline__ unsigned short f2bf(float f) {
    union { float f; unsigned u; } v; v.f = f;
    unsigned r = v.u + 0x7FFFu + ((v.u >> 16) & 1u);   // RNE
    return (unsigned short)(r >> 16);
}

__device__ __forceinline__ bf16x8 cvt8(float4 a, float4 b) {
    union { unsigned short s[8]; bf16x8 v; } r;
    r.s[0] = f2bf(a.x); r.s[1] = f2bf(a.y); r.s[2] = f2bf(a.z); r.s[3] = f2bf(a.w);
    r.s[4] = f2bf(b.x); r.s[5] = f2bf(b.y); r.s[6] = f2bf(b.z); r.s[7] = f2bf(b.w);
    return r.v;
}

__device__ __forceinline__ f32x4 fzero() { f32x4 z = {0.f, 0.f, 0.f, 0.f}; return z; }

// Swizzled index (ushort units): 16B granules XOR'd by row&15 (0 conflicts measured).
__device__ __forceinline__ int shidx(int m, int n) {          // H tile, stride 512
    return m * NH + (((n >> 3) ^ (m & 15)) << 3) + (n & 7);
}
__device__ __forceinline__ int shx(int m, int n) {            // X tile, stride 128
    return m * NDIN + ((((n >> 3) ^ (m & 15)) & 15) << 3) + (n & 7);
}

// ---------------- merged prep: fp32 [e][R][C] -> bf16 [e][C][R] ----------------
__global__ __launch_bounds__(256) void prep_weights(
    const float* __restrict__ W1, const float* __restrict__ W2, const float* __restrict__ W3,
    unsigned short* __restrict__ W1t, unsigned short* __restrict__ W2t, unsigned short* __restrict__ W3t)
{
    __shared__ float tile[64][65];
    const int t = blockIdx.x, e = blockIdx.y;
    const float* src; unsigned short* dst; int R, C, tr, tc;
    if (t < 16)      { src = W1; dst = W1t; R = NDIN; C = NH;  tr = t >> 3;        tc = t & 7;  }
    else if (t < 80) { src = W2; dst = W2t; R = NH;   C = NH;  tr = (t - 16) >> 3; tc = (t - 16) & 7; }
    else             { src = W3; dst = W3t; R = NH;   C = NDO; tr = t - 80;        tc = 0;      }
    const int r0 = tr * 64, c0 = tc * 64;
    const float* s = src + (size_t)e * R * C;
    unsigned short* d = dst + (size_t)e * R * C;
    const int tt = threadIdx.x;
#pragma unroll
    for (int i = 0; i < 4; ++i) {
        int f = i * 256 + tt;
        int r = f >> 4, c4 = (f & 15) * 4;
        const float4 v = *(const float4*)(s + (size_t)(r0 + r) * C + c0 + c4);
        tile[r][c4 + 0] = v.x; tile[r][c4 + 1] = v.y;
        tile[r][c4 + 2] = v.z; tile[r][c4 + 3] = v.w;
    }
    __syncthreads();
#pragma unroll
    for (int i = 0; i < 4; ++i) {
        int f = i * 256 + tt;
        int cc = f >> 4, rb = (f & 15) * 4;
        ushort4 o;
        o.x = f2bf(tile[rb + 0][cc]);
        o.y = f2bf(tile[rb + 1][cc]);
        o.z = f2bf(tile[rb + 2][cc]);
        o.w = f2bf(tile[rb + 3][cc]);
        *(ushort4*)(d + (size_t)(c0 + cc) * R + r0 + rb) = o;
    }
}

// ---------------- persistent fused MLP: 1 WG/CU, expert fixed, 8 rounds over batch ----------------
__global__ __launch_bounds__(512, 1) void moe_fused(
    const float* __restrict__ x,            // [B][E][DIN]
    const float* __restrict__ b1,           // [E][H]
    const float* __restrict__ b2,           // [E][H]
    const float* __restrict__ b3,           // [E][DOUT]
    const unsigned short* __restrict__ W1t, // [E][H][DIN]  bf16
    const unsigned short* __restrict__ W2t, // [E][H][H]    bf16
    const unsigned short* __restrict__ W3t, // [E][DOUT][H] bf16
    float* __restrict__ out)                // [B][DOUT]  (pre-zeroed)
{
    __shared__ unsigned short sMem[2 * 64 * NDIN + 2 * 64 * NH];  // 32KB X-dbuf + 2x64KB H = 160KB
    unsigned short* sX  = sMem;                    // [2][64*128]
    unsigned short* sHA = sMem + 2 * 64 * NDIN;    // H1
    unsigned short* sHB = sHA + 64 * NH;           // H2

    const int tid  = threadIdx.x;
    const int wave = tid >> 6;
    const int lane = tid & 63;
    const int q    = lane >> 4;
    const int l16  = lane & 15;
    const int hi2  = l16 >> 2;
    const int lo2  = l16 & 3;
    const int qe   = (q ^ lo2) * 8;
    const int blk  = blockIdx.x;
    const int e    = 2 * (blk & 7) + (blk >> 7);   // XCD-affine expert
    const int slot = (blk >> 3) & 15;
    const int nb   = wave * 64;

    // LDS A-frag bases (elements); read addr = base + ((kt^hi2)<<5)
    int aH[4], aX[4];
#pragma unroll
    for (int m = 0; m < 4; ++m) {
        aH[m] = (m * 16 + l16) * NH   + qe;
        aX[m] = (m * 16 + l16) * NDIN + qe;
    }

    // hoisted weight pointers / biases (constant over rounds)
    const unsigned short *wb1[4], *wb2[4];
#pragma unroll
    for (int n = 0; n < 4; ++n) {
        wb1[n] = W1t + (size_t)e * NH * NDIN + (size_t)(nb + n * 16 + l16) * NDIN + q * 8;
        wb2[n] = W2t + (size_t)e * NH * NH   + (size_t)(nb + n * 16 + l16) * NH   + q * 8;
    }
    const int n3 = wave & 3, mp = wave >> 2;
    const unsigned short* wb3 = W3t + (size_t)e * NDO * NH + (size_t)(n3 * 16 + l16) * NH + q * 8;
    float b1v[4], b2v[4];
#pragma unroll
    for (int n = 0; n < 4; ++n) {
        b1v[n] = b1[e * NH + nb + n * 16 + l16];
        b2v[n] = b2[e * NH + nb + n * 16 + l16];
    }
    const float b3v = b3[e * NDO + n3 * 16 + l16];
    int a3[2];
#pragma unroll
    for (int i = 0; i < 2; ++i) a3[i] = ((2 * mp + i) * 16 + l16) * NH + qe;

    // per-thread X staging geometry
    const int xr0 = tid >> 4, xc8 = (tid & 15) * 8;
    const int sxo0 = shx(xr0, xc8), sxo1 = shx(xr0 + 32, xc8);
    const float* xb = x + ((size_t)xr0 * NE + e) * NDIN + xc8;

    // ---- prologue: stage X(round 0) into parity 0 ----
    {
        const float* p0 = xb + (size_t)(slot * 64) * NE * NDIN;
        const float* p1 = p0 + (size_t)32 * NE * NDIN;
        float4 u0 = *(const float4*)p0, u1 = *(const float4*)(p0 + 4);
        float4 u2 = *(const float4*)p1, u3 = *(const float4*)(p1 + 4);
        *(bf16x8*)&sX[sxo0] = cvt8(u0, u1);
        *(bf16x8*)&sX[sxo1] = cvt8(u2, u3);
    }
    __syncthreads();   // B0: X(0) visible

    for (int r = 0; r < 8; ++r) {
        const int p = r & 1;
        unsigned short* sXp = sX + p * (64 * NDIN);
        unsigned short* sXn = sX + (p ^ 1) * (64 * NDIN);

        // ---------------- layer 1: sHA = relu(X @ W1 + b1), 4 kt ----------------
        {
            f32x4 acc[4][4];
#pragma unroll
            for (int m = 0; m < 4; ++m)
#pragma unroll
                for (int n = 0; n < 4; ++n) acc[m][n] = fzero();

            bf16x8 afr[3][4], bfr[3][4];
#pragma unroll
            for (int s = 0; s < 2; ++s)
#pragma unroll
                for (int n = 0; n < 4; ++n)
                    bfr[s][n] = *(const bf16x8*)(wb1[n] + s * 32);
#pragma unroll
            for (int s = 0; s < 2; ++s)
#pragma unroll
                for (int m = 0; m < 4; ++m)
                    afr[s][m] = *(const bf16x8*)&sXp[aX[m] + (((s ^ hi2) & 3) << 5)];

#pragma unroll
            for (int kt = 0; kt < 4; ++kt) {
                const int cur = kt % 3, pre = (kt + 2) % 3;
                if (kt < 2) {
#pragma unroll
                    for (int n = 0; n < 4; ++n)
                        bfr[pre][n] = *(const bf16x8*)(wb1[n] + (kt + 2) * 32);
#pragma unroll
                    for (int m = 0; m < 4; ++m)
                        afr[pre][m] = *(const bf16x8*)&sXp[aX[m] + ((((kt + 2) ^ hi2) & 3) << 5)];
                }
#pragma unroll
                for (int m = 0; m < 4; ++m)
#pragma unroll
                    for (int n = 0; n < 4; ++n)
                        acc[m][n] = __builtin_amdgcn_mfma_f32_16x16x32_bf16(
                            afr[cur][m], bfr[cur][n], acc[m][n], 0, 0, 0);
            }
            // H1 epilogue
#pragma unroll
            for (int n = 0; n < 4; ++n) {
                const int col = nb + n * 16 + l16;
#pragma unroll
                for (int m = 0; m < 4; ++m)
#pragma unroll
                    for (int rr = 0; rr < 4; ++rr) {
                        float v = acc[m][n][rr] + b1v[n];
                        sHA[shidx(m * 16 + q * 4 + rr, col)] = f2bf(fmaxf(v, 0.f));
                    }
            }
        }
        __syncthreads();   // B1: H1 visible (also fences L3(r-1) reads vs H2 writes below)

        // ---------------- layer 2: sHB = relu(H1 @ W2 + b2), 16 kt; X(r+1) mid-loop ----------------
        {
            f32x4 acc2[4][4];
#pragma unroll
            for (int m = 0; m < 4; ++m)
#pragma unroll
                for (int n = 0; n < 4; ++n) acc2[m][n] = fzero();

            bf16x8 afr[3][4], bfr[3][4];
#pragma unroll
            for (int s = 0; s < 2; ++s)
#pragma unroll
                for (int n = 0; n < 4; ++n)
                    bfr[s][n] = *(const bf16x8*)(wb2[n] + s * 32);
#pragma unroll
            for (int s = 0; s < 2; ++s)
#pragma unroll
                for (int m = 0; m < 4; ++m)
                    afr[s][m] = *(const bf16x8*)&sHA[aH[m] + ((s ^ hi2) << 5)];

            // issue next-round X loads (latency covered by first 8 kt)
            float4 xu0, xu1, xu2, xu3;
            if (r < 7) {
                const float* p0 = xb + (size_t)((slot + 16 * (r + 1)) * 64) * NE * NDIN;
                const float* p1 = p0 + (size_t)32 * NE * NDIN;
                xu0 = *(const float4*)p0; xu1 = *(const float4*)(p0 + 4);
                xu2 = *(const float4*)p1; xu3 = *(const float4*)(p1 + 4);
            }

#pragma unroll
            for (int kt = 0; kt < 8; ++kt) {
                const int cur = kt % 3, pre = (kt + 2) % 3;
#pragma unroll
                for (int n = 0; n < 4; ++n)
                    bfr[pre][n] = *(const bf16x8*)(wb2[n] + (kt + 2) * 32);
#pragma unroll
                for (int m = 0; m < 4; ++m)
                    afr[pre][m] = *(const bf16x8*)&sHA[aH[m] + (((kt + 2) ^ hi2) << 5)];
#pragma unroll
                for (int m = 0; m < 4; ++m)
#pragma unroll
                    for (int n = 0; n < 4; ++n)
                        acc2[m][n] = __builtin_amdgcn_mfma_f32_16x16x32_bf16(
                            afr[cur][m], bfr[cur][n], acc2[m][n], 0, 0, 0);
            }

            // write next-round X tile (other parity buffer; race-free, visible at B2)
            if (r < 7) {
                *(bf16x8*)&sXn[sxo0] = cvt8(xu0, xu1);
                *(bf16x8*)&sXn[sxo1] = cvt8(xu2, xu3);
            }

#pragma unroll
            for (int kt = 8; kt < 16; ++kt) {
                const int cur = kt % 3, pre = (kt + 2) % 3;
                if (kt < 14) {
#pragma unroll
                    for (int n = 0; n < 4; ++n)
                        bfr[pre][n] = *(const bf16x8*)(wb2[n] + (kt + 2) * 32);
#pragma unroll
                    for (int m = 0; m < 4; ++m)
                        afr[pre][m] = *(const bf16x8*)&sHA[aH[m] + (((kt + 2) ^ hi2) << 5)];
                }
#pragma unroll
                for (int m = 0; m < 4; ++m)
#pragma unroll
                    for (int n = 0; n < 4; ++n)
                        acc2[m][n] = __builtin_amdgcn_mfma_f32_16x16x32_bf16(
                            afr[cur][m], bfr[cur][n], acc2[m][n], 0, 0, 0);
            }

            // H2 epilogue (writes fenced from L3(r-1) readers by B1)
#pragma unroll
            for (int n = 0; n < 4; ++n) {
                const int col = nb + n * 16 + l16;
#pragma unroll
                for (int m = 0; m < 4; ++m)
#pragma unroll
                    for (int rr = 0; rr < 4; ++rr) {
                        float v = acc2[m][n][rr] + b2v[n];
                        sHB[shidx(m * 16 + q * 4 + rr, col)] = f2bf(fmaxf(v, 0.f));
                    }
            }
        }
        __syncthreads();   // B2: H2 + X(r+1) visible

        // ---------------- layer 3: O = H2 @ W3; rolling lookahead-3 in 4 slots ----------------
        {
            bf16x8 a3f[4][2], b3f[4];
#pragma unroll
            for (int s = 0; s < 3; ++s) {
#pragma unroll
                for (int i = 0; i < 2; ++i)
                    a3f[s][i] = *(const bf16x8*)&sHB[a3[i] + ((s ^ hi2) << 5)];
                b3f[s] = *(const bf16x8*)(wb3 + s * 32);
            }

            f32x4 oacc[2];
            oacc[0] = fzero(); oacc[1] = fzero();
#pragma unroll
            for (int kt = 0; kt < 16; ++kt) {
                const int cur = kt & 3;
                if (kt < 13) {
                    const int pre = (kt + 3) & 3;   // != cur always
#pragma unroll
                    for (int i = 0; i < 2; ++i)
                        a3f[pre][i] = *(const bf16x8*)&sHB[a3[i] + (((kt + 3) ^ hi2) << 5)];
                    b3f[pre] = *(const bf16x8*)(wb3 + (kt + 3) * 32);
                }
#pragma unroll
                for (int i = 0; i < 2; ++i)
                    oacc[i] = __builtin_amdgcn_mfma_f32_16x16x32_bf16(
                        a3f[cur][i], b3f[kt & 3], oacc[i], 0, 0, 0);
            }

            const int b0 = (slot + 16 * r) * 64;
            const int col = n3 * 16 + l16;
#pragma unroll
            for (int i = 0; i < 2; ++i)
#pragma unroll
                for (int rr = 0; rr < 4; ++rr) {
                    const int row = b0 + (2 * mp + i) * 16 + q * 4 + rr;
                    unsafeAtomicAdd(out + (size_t)row * NDO + col, oacc[i][rr] + b3v);
                }
        }
    }
}

extern "C" void kernel_launch(void* const* d_in, const int* in_sizes, int n_in,
                              void* d_out, int out_size, void* d_ws, size_t ws_size,
                              hipStream_t stream) {
    const float* x  = (const float*)d_in[0];
    const float* W1 = (const float*)d_in[1];
    const float* b1 = (const float*)d_in[2];
    const float* W2 = (const float*)d_in[3];
    const float* b2 = (const float*)d_in[4];
    const float* W3 = (const float*)d_in[5];
    const float* b3 = (const float*)d_in[6];
    float* out = (float*)d_out;

    unsigned short* W1t = (unsigned short*)d_ws;            // [E][H][DIN]
    unsigned short* W2t = W1t + (size_t)NE * NH * NDIN;     // [E][H][H]
    unsigned short* W3t = W2t + (size_t)NE * NH * NH;       // [E][DOUT][H]

    hipMemsetAsync(d_out, 0, (size_t)out_size * sizeof(float), stream);
    prep_weights<<<dim3(88, NE), 256, 0, stream>>>(W1, W2, W3, W1t, W2t, W3t);
    moe_fused<<<dim3(256), 512, 0, stream>>>(x, b1, b2, b3, W1t, W2t, W3t, out);
}

// Round 8
// 500.422 us; speedup vs baseline: 1.1368x; 1.1368x over previous
//
#include <hip/hip_runtime.h>

// out[b,o] = sum_e ( relu(relu(x[b,e,:]@W1[e]+b1[e])@W2[e]+b2[e]) @ W3[e] + b3[e] )
// E=16, DIN=128, H=512, DOUT=64, B=8192.  94.5 GFLOP.
//
// R8: persistent pipeline (R6 structure) with per-phase register budgeting.
//   Evidence R2/R6/R7: arch-VGPR cap for 512-thr blocks is 128 (launch_bounds arg 1 or 2)
//   or 64 (arg 4); AGPR accumulators don't count (R5: 124 arch + 64 agpr, no spill).
//   R6/R7 demanded ~220 arch -> 800 MB scratch spill. Fixes:
//     - A-frags depth-1 (32 regs), B-frags depth-2 only in L2 (48 regs), L1 all depth-1.
//     - X(r+1) global loads issued at L1 start, written to LDS right after L1's 4-kt
//       loop (regs live only in the short L1 phase). Fenced from readers by B1+B2.
//     - weight pointers/biases recomputed per phase (rematerializable, not loop-live).
//   Walls: MFMA ~11us; per-CU L2 weight stream 768KB/round * 8 -> ~45us (binding).

#define NE   16
#define NDIN 128
#define NH   512
#define NDO  64
#define NB   8192

using bf16x8 = __attribute__((ext_vector_type(8))) __bf16;
using f32x4  = __attribute__((ext_vector_type(4))) float;

__device__ __forceinline__ unsigned short f2bf(float f) {
    union { float f; unsigned u; } v; v.f = f;
    unsigned r = v.u + 0x7FFFu + ((v.u >> 16) & 1u);   // RNE
    return (unsigned short)(r >> 16);
}

__device__ __forceinline__ bf16x8 cvt8(float4 a, float4 b) {
    union { unsigned short s[8]; bf16x8 v; } r;
    r.s[0] = f2bf(a.x); r.s[1] = f2bf(a.y); r.s[2] = f2bf(a.z); r.s[3] = f2bf(a.w);
    r.s[4] = f2bf(b.x); r.s[5] = f2bf(b.y); r.s[6] = f2bf(b.z); r.s[7] = f2bf(b.w);
    return r.v;
}

__device__ __forceinline__ f32x4 fzero() { f32x4 z = {0.f, 0.f, 0.f, 0.f}; return z; }

// Swizzled index (ushort units): 16B granules XOR'd by row&15 (0 conflicts measured).
__device__ __forceinline__ int shidx(int m, int n) {          // H tile, stride 512
    return m * NH + (((n >> 3) ^ (m & 15)) << 3) + (n & 7);
}
__device__ __forceinline__ int shx(int m, int n) {            // X tile, stride 128
    return m * NDIN + ((((n >> 3) ^ (m & 15)) & 15) << 3) + (n & 7);
}

// ---------------- merged prep: fp32 [e][R][C] -> bf16 [e][C][R] ----------------
__global__ __launch_bounds__(256) void prep_weights(
    const float* __restrict__ W1, const float* __restrict__ W2, const float* __restrict__ W3,
    unsigned short* __restrict__ W1t, unsigned short* __restrict__ W2t, unsigned short* __restrict__ W3t)
{
    __shared__ float tile[64][65];
    const int t = blockIdx.x, e = blockIdx.y;
    const float* src; unsigned short* dst; int R, C, tr, tc;
    if (t < 16)      { src = W1; dst = W1t; R = NDIN; C = NH;  tr = t >> 3;        tc = t & 7;  }
    else if (t < 80) { src = W2; dst = W2t; R = NH;   C = NH;  tr = (t - 16) >> 3; tc = (t - 16) & 7; }
    else             { src = W3; dst = W3t; R = NH;   C = NDO; tr = t - 80;        tc = 0;      }
    const int r0 = tr * 64, c0 = tc * 64;
    const float* s = src + (size_t)e * R * C;
    unsigned short* d = dst + (size_t)e * R * C;
    const int tt = threadIdx.x;
#pragma unroll
    for (int i = 0; i < 4; ++i) {
        int f = i * 256 + tt;
        int r = f >> 4, c4 = (f & 15) * 4;
        const float4 v = *(const float4*)(s + (size_t)(r0 + r) * C + c0 + c4);
        tile[r][c4 + 0] = v.x; tile[r][c4 + 1] = v.y;
        tile[r][c4 + 2] = v.z; tile[r][c4 + 3] = v.w;
    }
    __syncthreads();
#pragma unroll
    for (int i = 0; i < 4; ++i) {
        int f = i * 256 + tt;
        int cc = f >> 4, rb = (f & 15) * 4;
        ushort4 o;
        o.x = f2bf(tile[rb + 0][cc]);
        o.y = f2bf(tile[rb + 1][cc]);
        o.z = f2bf(tile[rb + 2][cc]);
        o.w = f2bf(tile[rb + 3][cc]);
        *(ushort4*)(d + (size_t)(c0 + cc) * R + r0 + rb) = o;
    }
}

// ---------------- persistent fused MLP: 1 WG/CU, expert fixed, 8 rounds over batch ----------------
__global__ __launch_bounds__(512, 1) void moe_fused(
    const float* __restrict__ x,            // [B][E][DIN]
    const float* __restrict__ b1,           // [E][H]
    const float* __restrict__ b2,           // [E][H]
    const float* __restrict__ b3,           // [E][DOUT]
    const unsigned short* __restrict__ W1t, // [E][H][DIN]  bf16
    const unsigned short* __restrict__ W2t, // [E][H][H]    bf16
    const unsigned short* __restrict__ W3t, // [E][DOUT][H] bf16
    float* __restrict__ out)                // [B][DOUT]  (pre-zeroed)
{
    __shared__ unsigned short sMem[2 * 64 * NDIN + 2 * 64 * NH];  // 32KB X-dbuf + 2x64KB H = 160KB
    unsigned short* sX  = sMem;                    // [2][64*128]
    unsigned short* sHA = sMem + 2 * 64 * NDIN;    // H1
    unsigned short* sHB = sHA + 64 * NH;           // H2

    const int tid  = threadIdx.x;
    const int wave = tid >> 6;
    const int lane = tid & 63;
    const int q    = lane >> 4;
    const int l16  = lane & 15;
    const int hi2  = l16 >> 2;
    const int lo2  = l16 & 3;
    const int qe   = (q ^ lo2) * 8;
    const int blk  = blockIdx.x;
    const int e    = 2 * (blk & 7) + (blk >> 7);   // XCD-affine expert
    const int slot = (blk >> 3) & 15;
    const int nb   = wave * 64;
    const int n3   = wave & 3, mp = wave >> 2;

    // LDS A-frag bases (elements); read addr = base + ((kt^hi2)<<5)
    int aH[4], aX[4], a3[2];
#pragma unroll
    for (int m = 0; m < 4; ++m) {
        aH[m] = (m * 16 + l16) * NH   + qe;
        aX[m] = (m * 16 + l16) * NDIN + qe;
    }
#pragma unroll
    for (int i = 0; i < 2; ++i) a3[i] = ((2 * mp + i) * 16 + l16) * NH + qe;

    // per-thread X staging geometry
    const int xr0 = tid >> 4, xc8 = (tid & 15) * 8;
    const int sxo0 = shx(xr0, xc8), sxo1 = shx(xr0 + 32, xc8);
    const float* xb = x + ((size_t)xr0 * NE + e) * NDIN + xc8;

    // ---- prologue: stage X(round 0) into parity 0 ----
    {
        const float* p0 = xb + (size_t)(slot * 64) * NE * NDIN;
        const float* p1 = p0 + (size_t)32 * NE * NDIN;
        float4 u0 = *(const float4*)p0, u1 = *(const float4*)(p0 + 4);
        float4 u2 = *(const float4*)p1, u3 = *(const float4*)(p1 + 4);
        *(bf16x8*)&sX[sxo0] = cvt8(u0, u1);
        *(bf16x8*)&sX[sxo1] = cvt8(u2, u3);
    }
    __syncthreads();   // B0: X(0) visible

    for (int r = 0; r < 8; ++r) {
        const int p = r & 1;
        unsigned short* sXp = sX + p * (64 * NDIN);
        unsigned short* sXn = sX + (p ^ 1) * (64 * NDIN);

        // ---------------- layer 1: sHA = relu(X @ W1 + b1), 4 kt; X(r+1) staged here ----------------
        {
            // issue next-round X loads first (latency covered by the 4-kt MFMA loop)
            float4 xu0, xu1, xu2, xu3;
            if (r < 7) {
                const float* p0 = xb + (size_t)((slot + 16 * (r + 1)) * 64) * NE * NDIN;
                const float* p1 = p0 + (size_t)32 * NE * NDIN;
                xu0 = *(const float4*)p0; xu1 = *(const float4*)(p0 + 4);
                xu2 = *(const float4*)p1; xu3 = *(const float4*)(p1 + 4);
            }

            const unsigned short* wb1[4];
#pragma unroll
            for (int n = 0; n < 4; ++n)
                wb1[n] = W1t + (size_t)e * NH * NDIN + (size_t)(nb + n * 16 + l16) * NDIN + q * 8;

            f32x4 acc[4][4];
#pragma unroll
            for (int m = 0; m < 4; ++m)
#pragma unroll
                for (int n = 0; n < 4; ++n) acc[m][n] = fzero();

            bf16x8 afr[2][4], bfr[2][4];
#pragma unroll
            for (int n = 0; n < 4; ++n)
                bfr[0][n] = *(const bf16x8*)(wb1[n]);
#pragma unroll
            for (int m = 0; m < 4; ++m)
                afr[0][m] = *(const bf16x8*)&sXp[aX[m] + (((0 ^ hi2) & 3) << 5)];

#pragma unroll
            for (int kt = 0; kt < 4; ++kt) {
                const int cur = kt & 1, nxt = cur ^ 1;
                if (kt < 3) {
#pragma unroll
                    for (int n = 0; n < 4; ++n)
                        bfr[nxt][n] = *(const bf16x8*)(wb1[n] + (kt + 1) * 32);
#pragma unroll
                    for (int m = 0; m < 4; ++m)
                        afr[nxt][m] = *(const bf16x8*)&sXp[aX[m] + ((((kt + 1) ^ hi2) & 3) << 5)];
                }
#pragma unroll
                for (int m = 0; m < 4; ++m)
#pragma unroll
                    for (int n = 0; n < 4; ++n)
                        acc[m][n] = __builtin_amdgcn_mfma_f32_16x16x32_bf16(
                            afr[cur][m], bfr[cur][n], acc[m][n], 0, 0, 0);
            }

            // write next-round X tile into the other parity buffer (fenced by B1+B2)
            if (r < 7) {
                *(bf16x8*)&sXn[sxo0] = cvt8(xu0, xu1);
                *(bf16x8*)&sXn[sxo1] = cvt8(xu2, xu3);
            }

            // H1 epilogue
            float b1v[4];
#pragma unroll
            for (int n = 0; n < 4; ++n) b1v[n] = b1[e * NH + nb + n * 16 + l16];
#pragma unroll
            for (int n = 0; n < 4; ++n) {
                const int col = nb + n * 16 + l16;
#pragma unroll
                for (int m = 0; m < 4; ++m)
#pragma unroll
                    for (int rr = 0; rr < 4; ++rr) {
                        float v = acc[m][n][rr] + b1v[n];
                        sHA[shidx(m * 16 + q * 4 + rr, col)] = f2bf(fmaxf(v, 0.f));
                    }
            }
        }
        __syncthreads();   // B1: H1 visible; fences L3(r-1) sHB reads vs L2(r) sHB writes

        // ---------------- layer 2: sHB = relu(H1 @ W2 + b2), 16 kt ----------------
        {
            const unsigned short* wb2[4];
#pragma unroll
            for (int n = 0; n < 4; ++n)
                wb2[n] = W2t + (size_t)e * NH * NH + (size_t)(nb + n * 16 + l16) * NH + q * 8;

            f32x4 acc2[4][4];
#pragma unroll
            for (int m = 0; m < 4; ++m)
#pragma unroll
                for (int n = 0; n < 4; ++n) acc2[m][n] = fzero();

            bf16x8 afr[2][4], bfr[3][4];
#pragma unroll
            for (int s = 0; s < 2; ++s)                 // B depth-2 prologue
#pragma unroll
                for (int n = 0; n < 4; ++n)
                    bfr[s][n] = *(const bf16x8*)(wb2[n] + s * 32);
#pragma unroll
            for (int m = 0; m < 4; ++m)                 // A depth-1 prologue
                afr[0][m] = *(const bf16x8*)&sHA[aH[m] + ((0 ^ hi2) << 5)];

#pragma unroll
            for (int kt = 0; kt < 16; ++kt) {
                const int ca = kt & 1, na = ca ^ 1;     // A schedule (depth-1)
                const int cb = kt % 3;                  // B schedule (depth-2 in 3 slots)
                if (kt < 14) {
                    const int pb = (kt + 2) % 3;
#pragma unroll
                    for (int n = 0; n < 4; ++n)
                        bfr[pb][n] = *(const bf16x8*)(wb2[n] + (kt + 2) * 32);
                }
                if (kt < 15) {
#pragma unroll
                    for (int m = 0; m < 4; ++m)
                        afr[na][m] = *(const bf16x8*)&sHA[aH[m] + (((kt + 1) ^ hi2) << 5)];
                }
#pragma unroll
                for (int m = 0; m < 4; ++m)
#pragma unroll
                    for (int n = 0; n < 4; ++n)
                        acc2[m][n] = __builtin_amdgcn_mfma_f32_16x16x32_bf16(
                            afr[ca][m], bfr[cb][n], acc2[m][n], 0, 0, 0);
            }

            // H2 epilogue
            float b2v[4];
#pragma unroll
            for (int n = 0; n < 4; ++n) b2v[n] = b2[e * NH + nb + n * 16 + l16];
#pragma unroll
            for (int n = 0; n < 4; ++n) {
                const int col = nb + n * 16 + l16;
#pragma unroll
                for (int m = 0; m < 4; ++m)
#pragma unroll
                    for (int rr = 0; rr < 4; ++rr) {
                        float v = acc2[m][n][rr] + b2v[n];
                        sHB[shidx(m * 16 + q * 4 + rr, col)] = f2bf(fmaxf(v, 0.f));
                    }
            }
        }
        __syncthreads();   // B2: H2 + X(r+1) visible

        // ---------------- layer 3: O = H2 @ W3; rolling lookahead-3 in 4 slots (A and B) ----------------
        {
            const unsigned short* wb3 = W3t + (size_t)e * NDO * NH + (size_t)(n3 * 16 + l16) * NH + q * 8;

            bf16x8 a3f[4][2], b3f[4];
#pragma unroll
            for (int s = 0; s < 3; ++s) {
#pragma unroll
                for (int i = 0; i < 2; ++i)
                    a3f[s][i] = *(const bf16x8*)&sHB[a3[i] + ((s ^ hi2) << 5)];
                b3f[s] = *(const bf16x8*)(wb3 + s * 32);
            }

            f32x4 oacc[2];
            oacc[0] = fzero(); oacc[1] = fzero();
#pragma unroll
            for (int kt = 0; kt < 16; ++kt) {
                const int cur = kt & 3;
                if (kt < 13) {
                    const int pre = (kt + 3) & 3;   // != cur always
#pragma unroll
                    for (int i = 0; i < 2; ++i)
                        a3f[pre][i] = *(const bf16x8*)&sHB[a3[i] + (((kt + 3) ^ hi2) << 5)];
                    b3f[pre] = *(const bf16x8*)(wb3 + (kt + 3) * 32);
                }
#pragma unroll
                for (int i = 0; i < 2; ++i)
                    oacc[i] = __builtin_amdgcn_mfma_f32_16x16x32_bf16(
                        a3f[cur][i], b3f[cur], oacc[i], 0, 0, 0);
            }

            const float b3v = b3[e * NDO + n3 * 16 + l16];
            const int b0 = (slot + 16 * r) * 64;
            const int col = n3 * 16 + l16;
#pragma unroll
            for (int i = 0; i < 2; ++i)
#pragma unroll
                for (int rr = 0; rr < 4; ++rr) {
                    const int row = b0 + (2 * mp + i) * 16 + q * 4 + rr;
                    unsafeAtomicAdd(out + (size_t)row * NDO + col, oacc[i][rr] + b3v);
                }
        }
    }
}

extern "C" void kernel_launch(void* const* d_in, const int* in_sizes, int n_in,
                              void* d_out, int out_size, void* d_ws, size_t ws_size,
                              hipStream_t stream) {
    const float* x  = (const float*)d_in[0];
    const float* W1 = (const float*)d_in[1];
    const float* b1 = (const float*)d_in[2];
    const float* W2 = (const float*)d_in[3];
    const float* b2 = (const float*)d_in[4];
    const float* W3 = (const float*)d_in[5];
    const float* b3 = (const float*)d_in[6];
    float* out = (float*)d_out;

    unsigned short* W1t = (unsigned short*)d_ws;            // [E][H][DIN]
    unsigned short* W2t = W1t + (size_t)NE * NH * NDIN;     // [E][H][H]
    unsigned short* W3t = W2t + (size_t)NE * NH * NH;       // [E][DOUT][H]

    hipMemsetAsync(d_out, 0, (size_t)out_size * sizeof(float), stream);
    prep_weights<<<dim3(88, NE), 256, 0, stream>>>(W1, W2, W3, W1t, W2t, W3t);
    moe_fused<<<dim3(256), 512, 0, stream>>>(x, b1, b2, b3, W1t, W2t, W3t, out);
}

// Round 9
// 371.453 us; speedup vs baseline: 1.5315x; 1.3472x over previous
//
#include <hip/hip_runtime.h>

// out[b,o] = sum_e ( relu(relu(x[b,e,:]@W1[e]+b1[e])@W2[e]+b2[e]) @ W3[e] + b3[e] )
// E=16, DIN=128, H=512, DOUT=64, B=8192.  94.5 GFLOP.
//
// R9: M=128 tile, NON-persistent (persistent loop spills ~800MB scratch regardless of
//   source budgeting: R6/R7/R8; non-persistent per-phase blocks at (512,2) proved
//   spill-free at ~124 arch VGPRs: R3/R5).
//   R5 analysis: per kt its WG pulls 32KB W2 from L2 for 2.1 MFLOP = 64 FLOP/B; per-CU
//   MFMA peak needs 60 B/cyc = exactly the per-CU L2 share -> on the L2-BW knife edge.
//   M=128 doubles FLOP per weight byte (128 FLOP/B -> 30 B/cyc), halves WG count
//   (restart/barrier overhead), 32 MFMA/kt (155cyc issue) covers B-prefetch latency.
//  - LDS 160KB exact: X 32KB + single 128x512 H buffer, H1->H2 in place (barrier
//    separates last H1 read from H2 write).
//  - per wave: 8 m-tiles x 4 n-tiles, acc 128 AGPR, A single-buffered, B depth-2.
//  - bias folded into accumulator init.  XCD-affine expert mapping.

#define NE   16
#define NDIN 128
#define NH   512
#define NDO  64
#define NB   8192

using bf16x8 = __attribute__((ext_vector_type(8))) __bf16;
using f32x4  = __attribute__((ext_vector_type(4))) float;

__device__ __forceinline__ unsigned short f2bf(float f) {
    union { float f; unsigned u; } v; v.f = f;
    unsigned r = v.u + 0x7FFFu + ((v.u >> 16) & 1u);   // RNE
    return (unsigned short)(r >> 16);
}

__device__ __forceinline__ bf16x8 cvt8(float4 a, float4 b) {
    union { unsigned short s[8]; bf16x8 v; } r;
    r.s[0] = f2bf(a.x); r.s[1] = f2bf(a.y); r.s[2] = f2bf(a.z); r.s[3] = f2bf(a.w);
    r.s[4] = f2bf(b.x); r.s[5] = f2bf(b.y); r.s[6] = f2bf(b.z); r.s[7] = f2bf(b.w);
    return r.v;
}

// Swizzled index (ushort units): 16B granules XOR'd by row&15 (0 conflicts measured R3/R5).
__device__ __forceinline__ int shidx(int m, int n) {          // H tile, stride 512
    return m * NH + (((n >> 3) ^ (m & 15)) << 3) + (n & 7);
}
__device__ __forceinline__ int shx(int m, int n) {            // X tile, stride 128
    return m * NDIN + ((((n >> 3) ^ (m & 15)) & 15) << 3) + (n & 7);
}

// ---------------- merged prep: fp32 [e][R][C] -> bf16 [e][C][R] ----------------
__global__ __launch_bounds__(256) void prep_weights(
    const float* __restrict__ W1, const float* __restrict__ W2, const float* __restrict__ W3,
    unsigned short* __restrict__ W1t, unsigned short* __restrict__ W2t, unsigned short* __restrict__ W3t)
{
    __shared__ float tile[64][65];
    const int t = blockIdx.x, e = blockIdx.y;
    const float* src; unsigned short* dst; int R, C, tr, tc;
    if (t < 16)      { src = W1; dst = W1t; R = NDIN; C = NH;  tr = t >> 3;        tc = t & 7;  }
    else if (t < 80) { src = W2; dst = W2t; R = NH;   C = NH;  tr = (t - 16) >> 3; tc = (t - 16) & 7; }
    else             { src = W3; dst = W3t; R = NH;   C = NDO; tr = t - 80;        tc = 0;      }
    const int r0 = tr * 64, c0 = tc * 64;
    const float* s = src + (size_t)e * R * C;
    unsigned short* d = dst + (size_t)e * R * C;
    const int tt = threadIdx.x;
#pragma unroll
    for (int i = 0; i < 4; ++i) {
        int f = i * 256 + tt;
        int r = f >> 4, c4 = (f & 15) * 4;
        const float4 v = *(const float4*)(s + (size_t)(r0 + r) * C + c0 + c4);
        tile[r][c4 + 0] = v.x; tile[r][c4 + 1] = v.y;
        tile[r][c4 + 2] = v.z; tile[r][c4 + 3] = v.w;
    }
    __syncthreads();
#pragma unroll
    for (int i = 0; i < 4; ++i) {
        int f = i * 256 + tt;
        int cc = f >> 4, rb = (f & 15) * 4;
        ushort4 o;
        o.x = f2bf(tile[rb + 0][cc]);
        o.y = f2bf(tile[rb + 1][cc]);
        o.z = f2bf(tile[rb + 2][cc]);
        o.w = f2bf(tile[rb + 3][cc]);
        *(ushort4*)(d + (size_t)(c0 + cc) * R + r0 + rb) = o;
    }
}

// ---------------- fused 3-layer expert MLP: 128 rows x 1 expert per WG ----------------
__global__ __launch_bounds__(512, 2) void moe_fused(
    const float* __restrict__ x,            // [B][E][DIN]
    const float* __restrict__ b1,           // [E][H]
    const float* __restrict__ b2,           // [E][H]
    const float* __restrict__ b3,           // [E][DOUT]
    const unsigned short* __restrict__ W1t, // [E][H][DIN]  bf16
    const unsigned short* __restrict__ W2t, // [E][H][H]    bf16
    const unsigned short* __restrict__ W3t, // [E][DOUT][H] bf16
    float* __restrict__ out)                // [B][DOUT]  (pre-zeroed)
{
    __shared__ unsigned short sMem[128 * NDIN + 128 * NH];  // 32KB X + 128KB H = 160KB
    unsigned short* sX = sMem;
    unsigned short* sH = sMem + 128 * NDIN;

    const int tid  = threadIdx.x;
    const int wave = tid >> 6;
    const int lane = tid & 63;
    const int q    = lane >> 4;
    const int l16  = lane & 15;
    const int hi2  = l16 >> 2;
    const int lo2  = l16 & 3;
    const int qe   = (q ^ lo2) * 8;
    const int blk  = blockIdx.x;                  // 1024 blocks
    const int j    = blk >> 3;                    // [0,128)
    const int e    = 2 * (blk & 7) + (j >> 6);    // XCD-affine: XCD i handles experts {2i,2i+1}
    const int b0   = (j & 63) * 128;
    const int nb   = wave * 64;

    // ---- stage X: 128x128 fp32 -> bf16 swizzled LDS ----
#pragma unroll
    for (int i = 0; i < 4; ++i) {
        const int g = tid + i * 512;              // 2048 granules of 8
        const int row = g >> 4, c8 = (g & 15) * 8;
        const float* p = x + ((size_t)(b0 + row) * NE + e) * NDIN + c8;
        float4 u0 = *(const float4*)p;
        float4 u1 = *(const float4*)(p + 4);
        *(bf16x8*)&sX[shx(row, c8)] = cvt8(u0, u1);
    }
    __syncthreads();   // B0: X visible

    // ---------------- layer 1: sH = relu(X @ W1 + b1), 4 kt ----------------
    {
        const unsigned short* wb1[4];
        float b1v[4];
#pragma unroll
        for (int n = 0; n < 4; ++n) {
            wb1[n] = W1t + (size_t)e * NH * NDIN + (size_t)(nb + n * 16 + l16) * NDIN + q * 8;
            b1v[n] = b1[e * NH + nb + n * 16 + l16];
        }
        int aX[8];
#pragma unroll
        for (int m = 0; m < 8; ++m) aX[m] = (m * 16 + l16) * NDIN + qe;

        f32x4 acc[8][4];
#pragma unroll
        for (int m = 0; m < 8; ++m)
#pragma unroll
            for (int n = 0; n < 4; ++n) {
                f32x4 bv = {b1v[n], b1v[n], b1v[n], b1v[n]};
                acc[m][n] = bv;                    // bias folded into init
            }

        bf16x8 bfr[3][4], afr[8];
#pragma unroll
        for (int s = 0; s < 2; ++s)
#pragma unroll
            for (int n = 0; n < 4; ++n)
                bfr[s][n] = *(const bf16x8*)(wb1[n] + s * 32);

#pragma unroll
        for (int kt = 0; kt < 4; ++kt) {
            const int cb = kt % 3;
            if (kt < 2) {
                const int pb = (kt + 2) % 3;
#pragma unroll
                for (int n = 0; n < 4; ++n)
                    bfr[pb][n] = *(const bf16x8*)(wb1[n] + (kt + 2) * 32);
            }
#pragma unroll
            for (int m = 0; m < 8; ++m)
                afr[m] = *(const bf16x8*)&sX[aX[m] + (((kt ^ hi2) & 3) << 5)];
#pragma unroll
            for (int m = 0; m < 8; ++m)
#pragma unroll
                for (int n = 0; n < 4; ++n)
                    acc[m][n] = __builtin_amdgcn_mfma_f32_16x16x32_bf16(
                        afr[m], bfr[cb][n], acc[m][n], 0, 0, 0);
        }
        // H1 epilogue (relu + cvt; bias already in)
#pragma unroll
        for (int n = 0; n < 4; ++n) {
            const int col = nb + n * 16 + l16;
#pragma unroll
            for (int m = 0; m < 8; ++m)
#pragma unroll
                for (int rr = 0; rr < 4; ++rr)
                    sH[shidx(m * 16 + q * 4 + rr, col)] = f2bf(fmaxf(acc[m][n][rr], 0.f));
        }
    }
    __syncthreads();   // B1: H1 visible

    // ---------------- layer 2: acc2 = H1 @ W2 + b2, 16 kt (in regs) ----------------
    f32x4 acc2[8][4];
    {
        const unsigned short* wb2[4];
        float b2v[4];
#pragma unroll
        for (int n = 0; n < 4; ++n) {
            wb2[n] = W2t + (size_t)e * NH * NH + (size_t)(nb + n * 16 + l16) * NH + q * 8;
            b2v[n] = b2[e * NH + nb + n * 16 + l16];
        }
        int aH[8];
#pragma unroll
        for (int m = 0; m < 8; ++m) aH[m] = (m * 16 + l16) * NH + qe;

#pragma unroll
        for (int m = 0; m < 8; ++m)
#pragma unroll
            for (int n = 0; n < 4; ++n) {
                f32x4 bv = {b2v[n], b2v[n], b2v[n], b2v[n]};
                acc2[m][n] = bv;
            }

        bf16x8 bfr[3][4], afr[8];
#pragma unroll
        for (int s = 0; s < 2; ++s)
#pragma unroll
            for (int n = 0; n < 4; ++n)
                bfr[s][n] = *(const bf16x8*)(wb2[n] + s * 32);

#pragma unroll
        for (int kt = 0; kt < 16; ++kt) {
            const int cb = kt % 3;
            if (kt < 14) {
                const int pb = (kt + 2) % 3;
#pragma unroll
                for (int n = 0; n < 4; ++n)
                    bfr[pb][n] = *(const bf16x8*)(wb2[n] + (kt + 2) * 32);
            }
#pragma unroll
            for (int m = 0; m < 8; ++m)
                afr[m] = *(const bf16x8*)&sH[aH[m] + (((kt ^ hi2) & 15) << 5)];
#pragma unroll
            for (int m = 0; m < 8; ++m)
#pragma unroll
                for (int n = 0; n < 4; ++n)
                    acc2[m][n] = __builtin_amdgcn_mfma_f32_16x16x32_bf16(
                        afr[m], bfr[cb][n], acc2[m][n], 0, 0, 0);
        }
    }
    __syncthreads();   // B2: ALL H1 reads done -> safe to overwrite sH in place

    // H2 epilogue
#pragma unroll
    for (int n = 0; n < 4; ++n) {
        const int col = nb + n * 16 + l16;
#pragma unroll
        for (int m = 0; m < 8; ++m)
#pragma unroll
            for (int rr = 0; rr < 4; ++rr)
                sH[shidx(m * 16 + q * 4 + rr, col)] = f2bf(fmaxf(acc2[m][n][rr], 0.f));
    }
    __syncthreads();   // B3: H2 visible

    // ---------------- layer 3: O = H2 @ W3; wave = (m-half, n-tile) ----------------
    {
        const int n3 = wave & 3, mh = wave >> 2;   // mh in {0,1}: m-tiles mh*4 .. mh*4+3
        const unsigned short* wb3 = W3t + (size_t)e * NDO * NH + (size_t)(n3 * 16 + l16) * NH + q * 8;
        const float b3v = b3[e * NDO + n3 * 16 + l16];
        int a3[4];
#pragma unroll
        for (int i = 0; i < 4; ++i) a3[i] = ((mh * 4 + i) * 16 + l16) * NH + qe;

        bf16x8 a3f[4][4], b3f[4];
#pragma unroll
        for (int s = 0; s < 3; ++s) {              // preload chunks 0..2
#pragma unroll
            for (int i = 0; i < 4; ++i)
                a3f[s][i] = *(const bf16x8*)&sH[a3[i] + ((s ^ hi2) << 5)];
            b3f[s] = *(const bf16x8*)(wb3 + s * 32);
        }

        f32x4 oacc[4];
#pragma unroll
        for (int i = 0; i < 4; ++i) {
            f32x4 bv = {b3v, b3v, b3v, b3v};
            oacc[i] = bv;
        }

#pragma unroll
        for (int kt = 0; kt < 16; ++kt) {
            const int cur = kt & 3;
            if (kt < 13) {
                const int pre = (kt + 3) & 3;      // != cur always (lookahead-3 in 4 slots)
#pragma unroll
                for (int i = 0; i < 4; ++i)
                    a3f[pre][i] = *(const bf16x8*)&sH[a3[i] + (((kt + 3) ^ hi2) << 5)];
                b3f[pre] = *(const bf16x8*)(wb3 + (kt + 3) * 32);
            }
#pragma unroll
            for (int i = 0; i < 4; ++i)
                oacc[i] = __builtin_amdgcn_mfma_f32_16x16x32_bf16(
                    a3f[cur][i], b3f[cur], oacc[i], 0, 0, 0);
        }

        const int col = n3 * 16 + l16;
#pragma unroll
        for (int i = 0; i < 4; ++i)
#pragma unroll
            for (int rr = 0; rr < 4; ++rr) {
                const int row = b0 + (mh * 4 + i) * 16 + q * 4 + rr;
                unsafeAtomicAdd(out + (size_t)row * NDO + col, oacc[i][rr]);
            }
    }
}

extern "C" void kernel_launch(void* const* d_in, const int* in_sizes, int n_in,
                              void* d_out, int out_size, void* d_ws, size_t ws_size,
                              hipStream_t stream) {
    const float* x  = (const float*)d_in[0];
    const float* W1 = (const float*)d_in[1];
    const float* b1 = (const float*)d_in[2];
    const float* W2 = (const float*)d_in[3];
    const float* b2 = (const float*)d_in[4];
    const float* W3 = (const float*)d_in[5];
    const float* b3 = (const float*)d_in[6];
    float* out = (float*)d_out;

    unsigned short* W1t = (unsigned short*)d_ws;            // [E][H][DIN]
    unsigned short* W2t = W1t + (size_t)NE * NH * NDIN;     // [E][H][H]
    unsigned short* W3t = W2t + (size_t)NE * NH * NH;       // [E][DOUT][H]

    hipMemsetAsync(d_out, 0, (size_t)out_size * sizeof(float), stream);
    prep_weights<<<dim3(88, NE), 256, 0, stream>>>(W1, W2, W3, W1t, W2t, W3t);
    moe_fused<<<dim3(1024), 512, 0, stream>>>(x, b1, b2, b3, W1t, W2t, W3t, out);
}